// Round 13
// baseline (279.755 us; speedup 1.0000x reference)
//
#include <hip/hip_runtime.h>

#define NROWS 4096
#define DDIM  128
#define NHEAD 8

typedef __attribute__((ext_vector_type(8))) short    short8;
typedef __attribute__((ext_vector_type(8))) _Float16 half8;
typedef __attribute__((ext_vector_type(4))) float    floatx4;

__device__ __forceinline__ float bf2f(unsigned short u){
  unsigned v = ((unsigned)u) << 16;
  return __builtin_bit_cast(float, v);
}
__device__ __forceinline__ unsigned short f2bf(float f){
  unsigned u = __builtin_bit_cast(unsigned, f);
  u += 0x7FFFu + ((u >> 16) & 1u);
  return (unsigned short)(u >> 16);
}
__device__ __forceinline__ void split2(float v, unsigned short& hi, unsigned short& lo){
  hi = f2bf(v);
  lo = f2bf(v - bf2f(hi));
}
// async global->LDS, 16B per lane: LDS dest = wave-uniform base + lane*16.
__device__ __forceinline__ void async_cp16(const _Float16* g, _Float16* l){
  __builtin_amdgcn_global_load_lds(
      (const __attribute__((address_space(1))) void*)g,
      (__attribute__((address_space(3))) void*)l, 16, 0, 0);
}

// fp32 sentinels: 500=ws too small, 1000=in_sizes mismatch, 2000=launch fail.
__global__ void fill_kernel(float* __restrict__ out, float val, int n){
  int i = blockIdx.x * 256 + threadIdx.x;
  if (i < n) out[i] = val;
}

// ---------------------------------------------------------------------------
// Kernel 1: k = x@Wk[h], v = x@Wv[h]; fp16 outputs in MFMA fragment order
// with bank swizzle qX = quad ^ ((l4>>1)&3) baked in. 3-term bf16 MFMA.
// grid (16, NHEAD, 2): each block does FOUR 64-row tiles so each W half is
// staged once per block (4x less staging than one-tile blocks). block 256.
// ---------------------------------------------------------------------------
__global__ __launch_bounds__(256, 2) void proj_kernel(
    const float* __restrict__ x,
    const float* __restrict__ Wk, const float* __restrict__ Wv,
    _Float16* __restrict__ kfo, _Float16* __restrict__ vfo)
{
  __shared__ alignas(16) unsigned short wthi[DDIM][72];
  __shared__ alignas(16) unsigned short wtlo[DDIM][72];
  const int tid = threadIdx.x, lane = tid & 63, wave = tid >> 6;
  const int l4 = lane & 15, quad = lane >> 4;
  const int h = blockIdx.y, z = blockIdx.z;
  const float* W = (z == 0 ? Wk : Wv) + h * DDIM * DDIM;

  floatx4 acc[4][8];
#pragma unroll
  for (int t4 = 0; t4 < 4; t4++)
#pragma unroll
    for (int c = 0; c < 8; c++) acc[t4][c] = (floatx4)0.f;

  for (int fh = 0; fh < 2; fh++) {
    for (int i = tid; i < DDIM * 64; i += 256) {
      const int d = i >> 6, fl = i & 63;
      unsigned short hi, lo;
      split2(W[(fh * 64 + fl) * DDIM + d], hi, lo);
      wthi[d][fl] = hi; wtlo[d][fl] = lo;
    }
    __syncthreads();

#pragma unroll
    for (int t4 = 0; t4 < 4; t4++) {
      const int tile = blockIdx.x * 4 + t4;
      const float* xr = x + (size_t)(tile * 64 + wave * 16 + l4) * DDIM + fh * 64 + quad * 8;
      short8 ah[2], al[2];
#pragma unroll
      for (int t2 = 0; t2 < 2; t2++) {
        float4 v0 = *(const float4*)(xr + t2 * 32);
        float4 v1 = *(const float4*)(xr + t2 * 32 + 4);
        float xv[8] = {v0.x, v0.y, v0.z, v0.w, v1.x, v1.y, v1.z, v1.w};
#pragma unroll
        for (int j = 0; j < 8; j++) {
          unsigned short hi, lo; split2(xv[j], hi, lo);
          ah[t2][j] = (short)hi; al[t2][j] = (short)lo;
        }
      }
#pragma unroll
      for (int t2 = 0; t2 < 2; t2++) {
#pragma unroll
        for (int c = 0; c < 8; c++) {
          short8 bh = *(const short8*)(&wthi[c * 16 + l4][t2 * 32 + quad * 8]);
          short8 bl = *(const short8*)(&wtlo[c * 16 + l4][t2 * 32 + quad * 8]);
          acc[t4][c] = __builtin_amdgcn_mfma_f32_16x16x32_bf16(ah[t2], bh, acc[t4][c], 0, 0, 0);
          acc[t4][c] = __builtin_amdgcn_mfma_f32_16x16x32_bf16(al[t2], bh, acc[t4][c], 0, 0, 0);
          acc[t4][c] = __builtin_amdgcn_mfma_f32_16x16x32_bf16(ah[t2], bl, acc[t4][c], 0, 0, 0);
        }
      }
    }
    __syncthreads();
  }

  const int rb = wave * 16 + quad * 4;
#pragma unroll
  for (int t4 = 0; t4 < 4; t4++) {
    const int tile = blockIdx.x * 4 + t4;
    const size_t tilebase = (size_t)(h * 64 + tile) * 8192;
#pragma unroll
    for (int c = 0; c < 8; c++) {
      const int d = c * 16 + l4;
#pragma unroll
      for (int r = 0; r < 4; r++) {
        const int kl = rb + r;
        const float val = acc[t4][c][r];
        if (z == 0) {
          const int c2 = kl >> 4, l4k = kl & 15;
          const int tt = d >> 5, qd = (d >> 3) & 3, jj = d & 7;
          const int qX = qd ^ ((l4k >> 1) & 3);
          kfo[tilebase + (size_t)((c2 * 4 + tt) * 16 + l4k) * 32 + qX * 8 + jj] =
              (_Float16)val;
        } else {
          const int c2 = d >> 4, l4v = d & 15;
          const int tt = kl >> 5, qd = (kl >> 3) & 3, jj = kl & 7;
          const int qX = qd ^ ((l4v >> 1) & 3);
          vfo[tilebase + (size_t)((c2 * 2 + tt) * 16 + l4v) * 32 + qX * 8 + jj] =
              (_Float16)val;
        }
      }
    }
  }
}

// ---------------------------------------------------------------------------
// Kernel 2: flash attention, 128 q-rows/block, SPLIT-K x3. grid 768:
// h=bid&7 (XCD-affine), qt=(bid>>3)&31, s=bid>>8; kt in [64s/3, 64(s+1)/3).
// Wave owns 32 rows as 2x16-row groups; 16 K/V frag reads serve both.
// Alpha-skip: O/l rescale guarded by __any(alpha != 1) — exact, since
// exp(0)==1.0f when the running max is unchanged. LDS = 49152 B, 3 blk/CU.
// ---------------------------------------------------------------------------
union FlashLds {
  struct { unsigned short hi[DDIM][72], lo[DDIM][72]; } wq;  // 36864 B
  float qf[64][132];                                         // 33792 B
  struct { _Float16 k[8192], v[8192], p[4][2][1024]; } kv;   // 49152 B
};

__global__ __launch_bounds__(256, 2) void flash_kernel(
    const float* __restrict__ x, const float* __restrict__ Wq,
    const _Float16* __restrict__ kfo, const _Float16* __restrict__ vfo,
    _Float16* __restrict__ op, float* __restrict__ mb, float* __restrict__ lb)
{
  __shared__ alignas(16) FlashLds lds;
  const int tid = threadIdx.x, lane = tid & 63, wave = tid >> 6;
  const int l4 = lane & 15, quad = lane >> 4;
  const int h = blockIdx.x & 7, qt = (blockIdx.x >> 3) & 31, s = blockIdx.x >> 8;
  const int q0 = qt * 128;
  const int kt0 = (64 * s) / 3, kt1 = (64 * (s + 1)) / 3;

  half8 aq[2][4];  // [row-group g][t] fp16 A-frags

  // ---- phase 1: q = x @ Wq[h] for 128 rows, two 64-row sub-phases ----
  {
    floatx4 qacc[2][8];
#pragma unroll
    for (int sp = 0; sp < 2; sp++)
#pragma unroll
      for (int c = 0; c < 8; c++) qacc[sp][c] = (floatx4)0.f;

    const float* Wqh = Wq + h * DDIM * DDIM;
    for (int fh = 0; fh < 2; fh++) {
      for (int i = tid; i < DDIM * 64; i += 256) {
        const int d = i >> 6, fl = i & 63;
        unsigned short hi, lo;
        split2(Wqh[(fh * 64 + fl) * DDIM + d], hi, lo);
        lds.wq.hi[d][fl] = hi; lds.wq.lo[d][fl] = lo;
      }
      __syncthreads();
#pragma unroll
      for (int sp = 0; sp < 2; sp++) {
        const float* xr = x + (size_t)(q0 + sp * 64 + wave * 16 + l4) * DDIM + fh * 64 + quad * 8;
        short8 ah[2], al[2];
#pragma unroll
        for (int t2 = 0; t2 < 2; t2++) {
          float4 v0 = *(const float4*)(xr + t2 * 32);
          float4 v1 = *(const float4*)(xr + t2 * 32 + 4);
          float xv[8] = {v0.x, v0.y, v0.z, v0.w, v1.x, v1.y, v1.z, v1.w};
#pragma unroll
          for (int j = 0; j < 8; j++) {
            unsigned short hi, lo; split2(xv[j], hi, lo);
            ah[t2][j] = (short)hi; al[t2][j] = (short)lo;
          }
        }
#pragma unroll
        for (int t2 = 0; t2 < 2; t2++) {
#pragma unroll
          for (int c = 0; c < 8; c++) {
            short8 bh = *(const short8*)(&lds.wq.hi[c * 16 + l4][t2 * 32 + quad * 8]);
            short8 bl = *(const short8*)(&lds.wq.lo[c * 16 + l4][t2 * 32 + quad * 8]);
            qacc[sp][c] = __builtin_amdgcn_mfma_f32_16x16x32_bf16(ah[t2], bh, qacc[sp][c], 0, 0, 0);
            qacc[sp][c] = __builtin_amdgcn_mfma_f32_16x16x32_bf16(al[t2], bh, qacc[sp][c], 0, 0, 0);
            qacc[sp][c] = __builtin_amdgcn_mfma_f32_16x16x32_bf16(ah[t2], bl, qacc[sp][c], 0, 0, 0);
          }
        }
      }
      __syncthreads();
    }

#pragma unroll
    for (int sp = 0; sp < 2; sp++) {
#pragma unroll
      for (int c = 0; c < 8; c++)
#pragma unroll
        for (int r = 0; r < 4; r++)
          lds.qf[wave * 16 + quad * 4 + r][c * 16 + l4] = qacc[sp][c][r];
      __syncthreads();
      if ((wave >> 1) == sp) {
#pragma unroll
        for (int g = 0; g < 2; g++)
#pragma unroll
          for (int t = 0; t < 4; t++) {
            const float* qr = &lds.qf[(wave & 1) * 32 + g * 16 + l4][t * 32 + quad * 8];
            float4 v0 = *(const float4*)qr;
            float4 v1 = *(const float4*)(qr + 4);
            aq[g][t][0] = (_Float16)v0.x; aq[g][t][1] = (_Float16)v0.y;
            aq[g][t][2] = (_Float16)v0.z; aq[g][t][3] = (_Float16)v0.w;
            aq[g][t][4] = (_Float16)v1.x; aq[g][t][5] = (_Float16)v1.y;
            aq[g][t][6] = (_Float16)v1.z; aq[g][t][7] = (_Float16)v1.w;
          }
      }
      __syncthreads();
    }
  }

  // ---- kt loop ----
  float m_run[2][4];
#pragma unroll
  for (int g = 0; g < 2; g++)
#pragma unroll
    for (int r = 0; r < 4; r++) m_run[g][r] = -1e30f;
  floatx4 Oacc[2][8], lacc[2];
#pragma unroll
  for (int g = 0; g < 2; g++) {
    lacc[g] = (floatx4)0.f;
#pragma unroll
    for (int c = 0; c < 8; c++) Oacc[g][c] = (floatx4)0.f;
  }

  half8 vones;
#pragma unroll
  for (int j = 0; j < 8; j++) vones[j] = (_Float16)1.f;

  const _Float16* kfo_h = kfo + (size_t)h * 64 * 8192;
  const _Float16* vfo_h = vfo + (size_t)h * 64 * 8192;
  const int lq = (l4 * 4 + (quad ^ ((l4 >> 1) & 3))) * 8;

  for (int kt = kt0; kt < kt1; ++kt) {
    // ---- stage K/V tiles: linear async copy ----
    {
      const _Float16* ks = kfo_h + (size_t)kt * 8192 + wave * 2048 + lane * 8;
      const _Float16* vs = vfo_h + (size_t)kt * 8192 + wave * 2048 + lane * 8;
      _Float16* kd = &lds.kv.k[wave * 2048];
      _Float16* vd = &lds.kv.v[wave * 2048];
#pragma unroll
      for (int it = 0; it < 4; it++) {
        async_cp16(ks + it * 512, kd + it * 512);
        async_cp16(vs + it * 512, vd + it * 512);
      }
    }
    __syncthreads();  // b1: tiles staged

    // ---- S = Q @ K^T ----
    floatx4 Sf[2][4];
#pragma unroll
    for (int g = 0; g < 2; g++)
#pragma unroll
      for (int c = 0; c < 4; c++) Sf[g][c] = (floatx4)0.f;
#pragma unroll
    for (int t = 0; t < 4; t++) {
      half8 b[4];
#pragma unroll
      for (int c = 0; c < 4; c++)
        b[c] = *(const half8*)&lds.kv.k[(c * 4 + t) * 512 + lq];
#pragma unroll
      for (int g = 0; g < 2; g++)
#pragma unroll
        for (int c = 0; c < 4; c++)
          Sf[g][c] = __builtin_amdgcn_mfma_f32_16x16x32_f16(aq[g][t], b[c], Sf[g][c], 0, 0, 0);
    }

    // ---- per-wave register softmax per row group ----
    float alpha[2][4];
#pragma unroll
    for (int g = 0; g < 2; g++) {
      float mt[4];
#pragma unroll
      for (int r = 0; r < 4; r++)
        mt[r] = fmaxf(fmaxf(Sf[g][0][r], Sf[g][1][r]), fmaxf(Sf[g][2][r], Sf[g][3][r]));
#pragma unroll
      for (int mk = 1; mk <= 8; mk <<= 1)
#pragma unroll
        for (int r = 0; r < 4; r++) mt[r] = fmaxf(mt[r], __shfl_xor(mt[r], mk, 64));
#pragma unroll
      for (int r = 0; r < 4; r++) {
        const float mn = fmaxf(m_run[g][r], mt[r]);
        alpha[g][r] = __expf(m_run[g][r] - mn);
        m_run[g][r] = mn;
      }
#pragma unroll
      for (int r = 0; r < 4; r++)
#pragma unroll
        for (int c = 0; c < 4; c++) Sf[g][c][r] = __expf(Sf[g][c][r] - m_run[g][r]);
    }

    // ---- P: C-layout -> A-layout, wave-private frag-ordered LDS ----
#pragma unroll
    for (int g = 0; g < 2; g++)
#pragma unroll
      for (int c = 0; c < 4; c++)
#pragma unroll
        for (int r = 0; r < 4; r++)
          lds.kv.p[wave][g][((c * 2 + (l4 >> 3)) * 16 + quad * 4 + r) * 8 + (l4 & 7)] =
              (_Float16)Sf[g][c][r];

    // ---- rescale O/l only when the running max moved (alpha != 1) ----
#pragma unroll
    for (int g = 0; g < 2; g++) {
      const bool moved = (alpha[g][0] != 1.f) | (alpha[g][1] != 1.f) |
                         (alpha[g][2] != 1.f) | (alpha[g][3] != 1.f);
      if (__any(moved)) {
#pragma unroll
        for (int c = 0; c < 8; c++) {
          Oacc[g][c][0] *= alpha[g][0]; Oacc[g][c][1] *= alpha[g][1];
          Oacc[g][c][2] *= alpha[g][2]; Oacc[g][c][3] *= alpha[g][3];
        }
        lacc[g][0] *= alpha[g][0]; lacc[g][1] *= alpha[g][1];
        lacc[g][2] *= alpha[g][2]; lacc[g][3] *= alpha[g][3];
      }
    }
    // ---- O += P@V, l += P@ones ----
#pragma unroll
    for (int t = 0; t < 2; t++) {
      half8 ap[2];
#pragma unroll
      for (int g = 0; g < 2; g++) {
        ap[g] = *(const half8*)&lds.kv.p[wave][g][((t * 4 + quad) * 16 + l4) * 8];
        lacc[g] = __builtin_amdgcn_mfma_f32_16x16x32_f16(ap[g], vones, lacc[g], 0, 0, 0);
      }
#pragma unroll
      for (int c = 0; c < 8; c++) {
        half8 bv = *(const half8*)&lds.kv.v[(c * 2 + t) * 512 + lq];
#pragma unroll
        for (int g = 0; g < 2; g++)
          Oacc[g][c] = __builtin_amdgcn_mfma_f32_16x16x32_f16(ap[g], bv, Oacc[g][c], 0, 0, 0);
      }
    }
    __syncthreads();  // b2: all reads done -> safe to restage
  }

  // ---- epilogue: unnormalized partial O (fp16) + per-row (m, l) ----
#pragma unroll
  for (int g = 0; g < 2; g++) {
    const int rbase = wave * 32 + g * 16 + quad * 4;
    const size_t rowbase = (size_t)(s * NHEAD + h) * NROWS + q0 + rbase;
#pragma unroll
    for (int c = 0; c < 8; c++) {
      const int col = c * 16 + l4;
#pragma unroll
      for (int r = 0; r < 4; r++)
        op[(rowbase + r) * DDIM + col] = (_Float16)Oacc[g][c][r];
    }
    if (l4 == 0) {
#pragma unroll
      for (int r = 0; r < 4; r++) {
        mb[rowbase + r] = m_run[g][r];
        lb[rowbase + r] = lacc[g][r];
      }
    }
  }
}

// ---------------------------------------------------------------------------
// Kernel 3: merge 3 split-K partials + head-sum -> u. grid 4096, block 128.
// ---------------------------------------------------------------------------
__global__ __launch_bounds__(128) void merge_kernel(
    const _Float16* __restrict__ op, const float* __restrict__ mb,
    const float* __restrict__ lb, const float* __restrict__ Wm,
    float* __restrict__ u)
{
  __shared__ float sc[3][NHEAD];
  const int n = blockIdx.x, d = threadIdx.x;
  if (d < NHEAD) {
    const int h = d;
    float m0 = mb[(size_t)h * NROWS + n];
    float m1 = mb[(size_t)(NHEAD + h) * NROWS + n];
    float m2 = mb[(size_t)(2 * NHEAD + h) * NROWS + n];
    float l0 = lb[(size_t)h * NROWS + n];
    float l1 = lb[(size_t)(NHEAD + h) * NROWS + n];
    float l2 = lb[(size_t)(2 * NHEAD + h) * NROWS + n];
    const float m  = fmaxf(m0, fmaxf(m1, m2));
    const float a0 = __expf(m0 - m), a1 = __expf(m1 - m), a2 = __expf(m2 - m);
    const float invL = Wm[h] / (l0 * a0 + l1 * a1 + l2 * a2);
    sc[0][h] = a0 * invL;
    sc[1][h] = a1 * invL;
    sc[2][h] = a2 * invL;
  }
  __syncthreads();
  float acc = 0.f;
#pragma unroll
  for (int h = 0; h < NHEAD; h++) {
    acc += sc[0][h] * (float)op[((size_t)h * NROWS + n) * DDIM + d];
    acc += sc[1][h] * (float)op[((size_t)(NHEAD + h) * NROWS + n) * DDIM + d];
    acc += sc[2][h] * (float)op[((size_t)(2 * NHEAD + h) * NROWS + n) * DDIM + d];
  }
  u[(size_t)n * DDIM + d] = acc;
}

// ---------------------------------------------------------------------------
// Kernel 4: y = x + relu((x+u) @ Wg^T + bg), 3-term bf16 MFMA, Wg in LDS.
// grid 64 (64-row tiles), block 256.
// ---------------------------------------------------------------------------
__global__ __launch_bounds__(256, 2) void mlp_kernel(
    const float* __restrict__ x, const float* __restrict__ u,
    const float* __restrict__ Wg, const float* __restrict__ bg,
    float* __restrict__ out)
{
  __shared__ alignas(16) unsigned short wghi[DDIM][72];
  __shared__ alignas(16) unsigned short wglo[DDIM][72];
  const int tid = threadIdx.x, lane = tid & 63, wave = tid >> 6;
  const int l4 = lane & 15, quad = lane >> 4;
  const int r0 = blockIdx.x * 64;

  floatx4 acc[8];
#pragma unroll
  for (int c = 0; c < 8; c++) acc[c] = (floatx4)0.f;

  for (int fh = 0; fh < 2; fh++) {
    for (int i = tid; i < DDIM * 64; i += 256) {
      const int ii = i >> 6, jl = i & 63;
      unsigned short hi, lo;
      split2(Wg[ii * DDIM + fh * 64 + jl], hi, lo);
      wghi[ii][jl] = hi; wglo[ii][jl] = lo;
    }
    __syncthreads();

    const size_t xoff = (size_t)(r0 + wave * 16 + l4) * DDIM + fh * 64 + quad * 8;
    short8 ah[2], al[2];
#pragma unroll
    for (int t2 = 0; t2 < 2; t2++) {
      float4 x0 = *(const float4*)(x + xoff + t2 * 32);
      float4 x1 = *(const float4*)(x + xoff + t2 * 32 + 4);
      float4 u0 = *(const float4*)(u + xoff + t2 * 32);
      float4 u1 = *(const float4*)(u + xoff + t2 * 32 + 4);
      float hv[8] = {x0.x + u0.x, x0.y + u0.y, x0.z + u0.z, x0.w + u0.w,
                     x1.x + u1.x, x1.y + u1.y, x1.z + u1.z, x1.w + u1.w};
#pragma unroll
      for (int j = 0; j < 8; j++) {
        unsigned short hi, lo; split2(hv[j], hi, lo);
        ah[t2][j] = (short)hi; al[t2][j] = (short)lo;
      }
    }
#pragma unroll
    for (int t2 = 0; t2 < 2; t2++) {
#pragma unroll
      for (int c = 0; c < 8; c++) {
        short8 bh = *(const short8*)(&wghi[c * 16 + l4][t2 * 32 + quad * 8]);
        short8 bl = *(const short8*)(&wglo[c * 16 + l4][t2 * 32 + quad * 8]);
        acc[c] = __builtin_amdgcn_mfma_f32_16x16x32_bf16(ah[t2], bh, acc[c], 0, 0, 0);
        acc[c] = __builtin_amdgcn_mfma_f32_16x16x32_bf16(al[t2], bh, acc[c], 0, 0, 0);
        acc[c] = __builtin_amdgcn_mfma_f32_16x16x32_bf16(ah[t2], bl, acc[c], 0, 0, 0);
      }
    }
    __syncthreads();
  }

  const int rbase = wave * 16 + quad * 4;
#pragma unroll
  for (int c = 0; c < 8; c++) {
    const int col = c * 16 + l4;
    const float bgf = bg[col];
#pragma unroll
    for (int r = 0; r < 4; r++) {
      const size_t idx = (size_t)(r0 + rbase + r) * DDIM + col;
      out[idx] = x[idx] + fmaxf(acc[c][r] + bgf, 0.f);
    }
  }
}

extern "C" void kernel_launch(void* const* d_in, const int* in_sizes, int n_in,
                              void* d_out, int out_size, void* d_ws, size_t ws_size,
                              hipStream_t stream) {
  float* out = (float*)d_out;
  const int fill_blocks = (out_size + 255) / 256;

  const bool ok_sizes =
      n_in == 7 &&
      in_sizes[0] == NROWS * DDIM &&
      in_sizes[1] == NHEAD * DDIM * DDIM &&
      in_sizes[2] == NHEAD * DDIM * DDIM &&
      in_sizes[3] == NHEAD * DDIM * DDIM &&
      in_sizes[4] == NHEAD &&
      in_sizes[5] == DDIM * DDIM &&
      in_sizes[6] == DDIM &&
      out_size == NROWS * DDIM;
  if (!ok_sizes) {
    fill_kernel<<<fill_blocks, 256, 0, stream>>>(out, 1000.f, out_size);
    return;
  }

  // ws: u 2MB + kfo 8.4 + vfo 8.4 + op(3) 25.2 + mb/lb 0.8 = 44.8MB
  const size_t HND = (size_t)NHEAD * NROWS * DDIM;
  const size_t ND  = (size_t)NROWS * DDIM;
  const size_t need = ND * 4 + 2 * HND * 2 + 3 * HND * 2 + 3 * NHEAD * NROWS * 8;
  if (ws_size < need) {
    fill_kernel<<<fill_blocks, 256, 0, stream>>>(out, 500.f, out_size);
    return;
  }

  const float* x  = (const float*)d_in[0];
  const float* Wk = (const float*)d_in[1];
  const float* Wq = (const float*)d_in[2];
  const float* Wv = (const float*)d_in[3];
  const float* Wm = (const float*)d_in[4];
  const float* Wg = (const float*)d_in[5];
  const float* bg = (const float*)d_in[6];

  float*     u   = (float*)d_ws;
  _Float16*  kfo = (_Float16*)(u + ND);
  _Float16*  vfo = kfo + HND;
  _Float16*  op  = vfo + HND;
  float*     mb  = (float*)(op + 3 * HND);
  float*     lb  = mb + 3 * NHEAD * NROWS;

  (void)hipGetLastError();
  proj_kernel<<<dim3(16, NHEAD, 2), 256, 0, stream>>>(x, Wk, Wv, kfo, vfo);
  flash_kernel<<<dim3(768), 256, 0, stream>>>(x, Wq, kfo, vfo, op, mb, lb);
  merge_kernel<<<dim3(4096), 128, 0, stream>>>(op, mb, lb, Wm, u);
  mlp_kernel<<<dim3(64), 256, 0, stream>>>(x, u, Wg, bg, out);
  if (hipGetLastError() != hipSuccess) {
    fill_kernel<<<fill_blocks, 256, 0, stream>>>(out, 2000.f, out_size);
  }
}

// Round 14
// 254.754 us; speedup vs baseline: 1.0981x; 1.0981x over previous
//
#include <hip/hip_runtime.h>

#define NROWS 4096
#define DDIM  128
#define NHEAD 8

typedef __attribute__((ext_vector_type(8))) short    short8;
typedef __attribute__((ext_vector_type(8))) _Float16 half8;
typedef __attribute__((ext_vector_type(4))) float    floatx4;

__device__ __forceinline__ float bf2f(unsigned short u){
  unsigned v = ((unsigned)u) << 16;
  return __builtin_bit_cast(float, v);
}
__device__ __forceinline__ unsigned short f2bf(float f){
  unsigned u = __builtin_bit_cast(unsigned, f);
  u += 0x7FFFu + ((u >> 16) & 1u);
  return (unsigned short)(u >> 16);
}
__device__ __forceinline__ void split2(float v, unsigned short& hi, unsigned short& lo){
  hi = f2bf(v);
  lo = f2bf(v - bf2f(hi));
}
// async global->LDS, 16B per lane: LDS dest = wave-uniform base + lane*16.
__device__ __forceinline__ void async_cp16(const _Float16* g, _Float16* l){
  __builtin_amdgcn_global_load_lds(
      (const __attribute__((address_space(1))) void*)g,
      (__attribute__((address_space(3))) void*)l, 16, 0, 0);
}

// fp32 sentinels: 500=ws too small, 1000=in_sizes mismatch, 2000=launch fail.
__global__ void fill_kernel(float* __restrict__ out, float val, int n){
  int i = blockIdx.x * 256 + threadIdx.x;
  if (i < n) out[i] = val;
}

// ---------------------------------------------------------------------------
// Kernel 1: k = x@Wk[h], v = x@Wv[h]; fp16 outputs in MFMA fragment order
// with bank swizzle qX = quad ^ ((l4>>1)&3) baked in. 3-term bf16 MFMA.
// grid (16, NHEAD, 2): four 64-row tiles per block, W staged once per half.
// ---------------------------------------------------------------------------
__global__ __launch_bounds__(256, 2) void proj_kernel(
    const float* __restrict__ x,
    const float* __restrict__ Wk, const float* __restrict__ Wv,
    _Float16* __restrict__ kfo, _Float16* __restrict__ vfo)
{
  __shared__ alignas(16) unsigned short wthi[DDIM][72];
  __shared__ alignas(16) unsigned short wtlo[DDIM][72];
  const int tid = threadIdx.x, lane = tid & 63, wave = tid >> 6;
  const int l4 = lane & 15, quad = lane >> 4;
  const int h = blockIdx.y, z = blockIdx.z;
  const float* W = (z == 0 ? Wk : Wv) + h * DDIM * DDIM;

  floatx4 acc[4][8];
#pragma unroll
  for (int t4 = 0; t4 < 4; t4++)
#pragma unroll
    for (int c = 0; c < 8; c++) acc[t4][c] = (floatx4)0.f;

  for (int fh = 0; fh < 2; fh++) {
    for (int i = tid; i < DDIM * 64; i += 256) {
      const int d = i >> 6, fl = i & 63;
      unsigned short hi, lo;
      split2(W[(fh * 64 + fl) * DDIM + d], hi, lo);
      wthi[d][fl] = hi; wtlo[d][fl] = lo;
    }
    __syncthreads();

#pragma unroll
    for (int t4 = 0; t4 < 4; t4++) {
      const int tile = blockIdx.x * 4 + t4;
      const float* xr = x + (size_t)(tile * 64 + wave * 16 + l4) * DDIM + fh * 64 + quad * 8;
      short8 ah[2], al[2];
#pragma unroll
      for (int t2 = 0; t2 < 2; t2++) {
        float4 v0 = *(const float4*)(xr + t2 * 32);
        float4 v1 = *(const float4*)(xr + t2 * 32 + 4);
        float xv[8] = {v0.x, v0.y, v0.z, v0.w, v1.x, v1.y, v1.z, v1.w};
#pragma unroll
        for (int j = 0; j < 8; j++) {
          unsigned short hi, lo; split2(xv[j], hi, lo);
          ah[t2][j] = (short)hi; al[t2][j] = (short)lo;
        }
      }
#pragma unroll
      for (int t2 = 0; t2 < 2; t2++) {
#pragma unroll
        for (int c = 0; c < 8; c++) {
          short8 bh = *(const short8*)(&wthi[c * 16 + l4][t2 * 32 + quad * 8]);
          short8 bl = *(const short8*)(&wtlo[c * 16 + l4][t2 * 32 + quad * 8]);
          acc[t4][c] = __builtin_amdgcn_mfma_f32_16x16x32_bf16(ah[t2], bh, acc[t4][c], 0, 0, 0);
          acc[t4][c] = __builtin_amdgcn_mfma_f32_16x16x32_bf16(al[t2], bh, acc[t4][c], 0, 0, 0);
          acc[t4][c] = __builtin_amdgcn_mfma_f32_16x16x32_bf16(ah[t2], bl, acc[t4][c], 0, 0, 0);
        }
      }
    }
    __syncthreads();
  }

  const int rb = wave * 16 + quad * 4;
#pragma unroll
  for (int t4 = 0; t4 < 4; t4++) {
    const int tile = blockIdx.x * 4 + t4;
    const size_t tilebase = (size_t)(h * 64 + tile) * 8192;
#pragma unroll
    for (int c = 0; c < 8; c++) {
      const int d = c * 16 + l4;
#pragma unroll
      for (int r = 0; r < 4; r++) {
        const int kl = rb + r;
        const float val = acc[t4][c][r];
        if (z == 0) {
          const int c2 = kl >> 4, l4k = kl & 15;
          const int tt = d >> 5, qd = (d >> 3) & 3, jj = d & 7;
          const int qX = qd ^ ((l4k >> 1) & 3);
          kfo[tilebase + (size_t)((c2 * 4 + tt) * 16 + l4k) * 32 + qX * 8 + jj] =
              (_Float16)val;
        } else {
          const int c2 = d >> 4, l4v = d & 15;
          const int tt = kl >> 5, qd = (kl >> 3) & 3, jj = kl & 7;
          const int qX = qd ^ ((l4v >> 1) & 3);
          vfo[tilebase + (size_t)((c2 * 2 + tt) * 16 + l4v) * 32 + qX * 8 + jj] =
              (_Float16)val;
        }
      }
    }
  }
}

// ---------------------------------------------------------------------------
// Kernel 2: flash attention, 128 q-rows/block, SPLIT-K x2, ONE barrier/iter.
// grid 512: h=bid&7 (XCD-affine), qt=(bid>>3)&31, s=bid>>8.
// K double-buffered in LDS: prefetch for kt+1 issued AFTER the barrier, so
// the next barrier's vmcnt drain gives it a full iteration to land.
// V fragments load per-wave global->VGPR at iter start (XCD-local L2) and
// are consumed at PV — S+softmax hides their latency.
// Wave owns 32 rows as 2x16 groups; alpha-skip on unchanged running max.
// LDS = 49152 B.
// ---------------------------------------------------------------------------
union FlashLds {
  struct { unsigned short hi[DDIM][72], lo[DDIM][72]; } wq;  // 36864 B
  float qf[64][132];                                         // 33792 B
  struct { _Float16 k[2][8192], p[4][2][1024]; } kv;         // 49152 B
};

__global__ __launch_bounds__(256, 2) void flash_kernel(
    const float* __restrict__ x, const float* __restrict__ Wq,
    const _Float16* __restrict__ kfo, const _Float16* __restrict__ vfo,
    _Float16* __restrict__ op, float* __restrict__ mb, float* __restrict__ lb)
{
  __shared__ alignas(16) FlashLds lds;
  const int tid = threadIdx.x, lane = tid & 63, wave = tid >> 6;
  const int l4 = lane & 15, quad = lane >> 4;
  const int h = blockIdx.x & 7, qt = (blockIdx.x >> 3) & 31, s = blockIdx.x >> 8;
  const int q0 = qt * 128;

  half8 aq[2][4];  // [row-group g][t] fp16 A-frags

  // ---- phase 1: q = x @ Wq[h] for 128 rows, two 64-row sub-phases ----
  {
    floatx4 qacc[2][8];
#pragma unroll
    for (int sp = 0; sp < 2; sp++)
#pragma unroll
      for (int c = 0; c < 8; c++) qacc[sp][c] = (floatx4)0.f;

    const float* Wqh = Wq + h * DDIM * DDIM;
    for (int fh = 0; fh < 2; fh++) {
      for (int i = tid; i < DDIM * 64; i += 256) {
        const int d = i >> 6, fl = i & 63;
        unsigned short hi, lo;
        split2(Wqh[(fh * 64 + fl) * DDIM + d], hi, lo);
        lds.wq.hi[d][fl] = hi; lds.wq.lo[d][fl] = lo;
      }
      __syncthreads();
#pragma unroll
      for (int sp = 0; sp < 2; sp++) {
        const float* xr = x + (size_t)(q0 + sp * 64 + wave * 16 + l4) * DDIM + fh * 64 + quad * 8;
        short8 ah[2], al[2];
#pragma unroll
        for (int t2 = 0; t2 < 2; t2++) {
          float4 v0 = *(const float4*)(xr + t2 * 32);
          float4 v1 = *(const float4*)(xr + t2 * 32 + 4);
          float xv[8] = {v0.x, v0.y, v0.z, v0.w, v1.x, v1.y, v1.z, v1.w};
#pragma unroll
          for (int j = 0; j < 8; j++) {
            unsigned short hi, lo; split2(xv[j], hi, lo);
            ah[t2][j] = (short)hi; al[t2][j] = (short)lo;
          }
        }
#pragma unroll
        for (int t2 = 0; t2 < 2; t2++) {
#pragma unroll
          for (int c = 0; c < 8; c++) {
            short8 bh = *(const short8*)(&lds.wq.hi[c * 16 + l4][t2 * 32 + quad * 8]);
            short8 bl = *(const short8*)(&lds.wq.lo[c * 16 + l4][t2 * 32 + quad * 8]);
            qacc[sp][c] = __builtin_amdgcn_mfma_f32_16x16x32_bf16(ah[t2], bh, qacc[sp][c], 0, 0, 0);
            qacc[sp][c] = __builtin_amdgcn_mfma_f32_16x16x32_bf16(al[t2], bh, qacc[sp][c], 0, 0, 0);
            qacc[sp][c] = __builtin_amdgcn_mfma_f32_16x16x32_bf16(ah[t2], bl, qacc[sp][c], 0, 0, 0);
          }
        }
      }
      __syncthreads();
    }

#pragma unroll
    for (int sp = 0; sp < 2; sp++) {
#pragma unroll
      for (int c = 0; c < 8; c++)
#pragma unroll
        for (int r = 0; r < 4; r++)
          lds.qf[wave * 16 + quad * 4 + r][c * 16 + l4] = qacc[sp][c][r];
      __syncthreads();
      if ((wave >> 1) == sp) {
#pragma unroll
        for (int g = 0; g < 2; g++)
#pragma unroll
          for (int t = 0; t < 4; t++) {
            const float* qr = &lds.qf[(wave & 1) * 32 + g * 16 + l4][t * 32 + quad * 8];
            float4 v0 = *(const float4*)qr;
            float4 v1 = *(const float4*)(qr + 4);
            aq[g][t][0] = (_Float16)v0.x; aq[g][t][1] = (_Float16)v0.y;
            aq[g][t][2] = (_Float16)v0.z; aq[g][t][3] = (_Float16)v0.w;
            aq[g][t][4] = (_Float16)v1.x; aq[g][t][5] = (_Float16)v1.y;
            aq[g][t][6] = (_Float16)v1.z; aq[g][t][7] = (_Float16)v1.w;
          }
      }
      __syncthreads();
    }
  }

  // ---- kt loop: one barrier per iteration ----
  float m_run[2][4];
#pragma unroll
  for (int g = 0; g < 2; g++)
#pragma unroll
    for (int r = 0; r < 4; r++) m_run[g][r] = -1e30f;
  floatx4 Oacc[2][8], lacc[2];
#pragma unroll
  for (int g = 0; g < 2; g++) {
    lacc[g] = (floatx4)0.f;
#pragma unroll
    for (int c = 0; c < 8; c++) Oacc[g][c] = (floatx4)0.f;
  }

  half8 vones;
#pragma unroll
  for (int j = 0; j < 8; j++) vones[j] = (_Float16)1.f;

  const _Float16* kfo_h = kfo + (size_t)h * 64 * 8192;
  const _Float16* vfo_h = vfo + (size_t)h * 64 * 8192;
  const int lq = (l4 * 4 + (quad ^ ((l4 >> 1) & 3))) * 8;
  const int kt0 = s * 32, kt1 = kt0 + 32;

  // preload K(kt0) into buffer 0 (kt0 is even for both s)
  {
    const _Float16* ks = kfo_h + (size_t)kt0 * 8192 + wave * 2048 + lane * 8;
    _Float16* kd = &lds.kv.k[0][wave * 2048];
#pragma unroll
    for (int it = 0; it < 4; it++) async_cp16(ks + it * 512, kd + it * 512);
  }

  for (int kt = kt0; kt < kt1; ++kt) {
    const int cur = kt & 1;
    __syncthreads();  // drains K(kt) copies; all waves done with k[cur^1]

    // ---- V frags for THIS tile: global (L2) -> registers, used at PV ----
    half8 vfrag[8][2];
    {
      const _Float16* vtb = vfo_h + (size_t)kt * 8192;
#pragma unroll
      for (int c = 0; c < 8; c++)
#pragma unroll
        for (int t = 0; t < 2; t++)
          vfrag[c][t] = *(const half8*)(vtb + (c * 2 + t) * 512 + lq);
    }
    // ---- prefetch K(kt+1) into the other buffer ----
    if (kt + 1 < kt1) {
      const _Float16* ks = kfo_h + (size_t)(kt + 1) * 8192 + wave * 2048 + lane * 8;
      _Float16* kd = &lds.kv.k[cur ^ 1][wave * 2048];
#pragma unroll
      for (int it = 0; it < 4; it++) async_cp16(ks + it * 512, kd + it * 512);
    }

    // ---- S = Q @ K^T (K from LDS buffer cur) ----
    floatx4 Sf[2][4];
#pragma unroll
    for (int g = 0; g < 2; g++)
#pragma unroll
      for (int c = 0; c < 4; c++) Sf[g][c] = (floatx4)0.f;
#pragma unroll
    for (int t = 0; t < 4; t++) {
      half8 b[4];
#pragma unroll
      for (int c = 0; c < 4; c++)
        b[c] = *(const half8*)&lds.kv.k[cur][(c * 4 + t) * 512 + lq];
#pragma unroll
      for (int g = 0; g < 2; g++)
#pragma unroll
        for (int c = 0; c < 4; c++)
          Sf[g][c] = __builtin_amdgcn_mfma_f32_16x16x32_f16(aq[g][t], b[c], Sf[g][c], 0, 0, 0);
    }

    // ---- per-wave register softmax per row group ----
    float alpha[2][4];
#pragma unroll
    for (int g = 0; g < 2; g++) {
      float mt[4];
#pragma unroll
      for (int r = 0; r < 4; r++)
        mt[r] = fmaxf(fmaxf(Sf[g][0][r], Sf[g][1][r]), fmaxf(Sf[g][2][r], Sf[g][3][r]));
#pragma unroll
      for (int mk = 1; mk <= 8; mk <<= 1)
#pragma unroll
        for (int r = 0; r < 4; r++) mt[r] = fmaxf(mt[r], __shfl_xor(mt[r], mk, 64));
#pragma unroll
      for (int r = 0; r < 4; r++) {
        const float mn = fmaxf(m_run[g][r], mt[r]);
        alpha[g][r] = __expf(m_run[g][r] - mn);
        m_run[g][r] = mn;
      }
#pragma unroll
      for (int r = 0; r < 4; r++)
#pragma unroll
        for (int c = 0; c < 4; c++) Sf[g][c][r] = __expf(Sf[g][c][r] - m_run[g][r]);
    }

    // ---- P: C-layout -> A-layout, wave-private frag-ordered LDS ----
#pragma unroll
    for (int g = 0; g < 2; g++)
#pragma unroll
      for (int c = 0; c < 4; c++)
#pragma unroll
        for (int r = 0; r < 4; r++)
          lds.kv.p[wave][g][((c * 2 + (l4 >> 3)) * 16 + quad * 4 + r) * 8 + (l4 & 7)] =
              (_Float16)Sf[g][c][r];

    // ---- rescale O/l only when the running max moved ----
#pragma unroll
    for (int g = 0; g < 2; g++) {
      const bool moved = (alpha[g][0] != 1.f) | (alpha[g][1] != 1.f) |
                         (alpha[g][2] != 1.f) | (alpha[g][3] != 1.f);
      if (__any(moved)) {
#pragma unroll
        for (int c = 0; c < 8; c++) {
          Oacc[g][c][0] *= alpha[g][0]; Oacc[g][c][1] *= alpha[g][1];
          Oacc[g][c][2] *= alpha[g][2]; Oacc[g][c][3] *= alpha[g][3];
        }
        lacc[g][0] *= alpha[g][0]; lacc[g][1] *= alpha[g][1];
        lacc[g][2] *= alpha[g][2]; lacc[g][3] *= alpha[g][3];
      }
    }
    // ---- O += P@V (V from registers), l += P@ones ----
#pragma unroll
    for (int t = 0; t < 2; t++) {
      half8 ap[2];
#pragma unroll
      for (int g = 0; g < 2; g++) {
        ap[g] = *(const half8*)&lds.kv.p[wave][g][((t * 4 + quad) * 16 + l4) * 8];
        lacc[g] = __builtin_amdgcn_mfma_f32_16x16x32_f16(ap[g], vones, lacc[g], 0, 0, 0);
      }
#pragma unroll
      for (int c = 0; c < 8; c++)
#pragma unroll
        for (int g = 0; g < 2; g++)
          Oacc[g][c] = __builtin_amdgcn_mfma_f32_16x16x32_f16(ap[g], vfrag[c][t], Oacc[g][c], 0, 0, 0);
    }
    // no trailing barrier: next iteration's barrier covers both hazards
  }

  // ---- epilogue: unnormalized partial O (fp16) + per-row (m, l) ----
#pragma unroll
  for (int g = 0; g < 2; g++) {
    const int rbase = wave * 32 + g * 16 + quad * 4;
    const size_t rowbase = (size_t)(s * NHEAD + h) * NROWS + q0 + rbase;
#pragma unroll
    for (int c = 0; c < 8; c++) {
      const int col = c * 16 + l4;
#pragma unroll
      for (int r = 0; r < 4; r++)
        op[(rowbase + r) * DDIM + col] = (_Float16)Oacc[g][c][r];
    }
    if (l4 == 0) {
#pragma unroll
      for (int r = 0; r < 4; r++) {
        mb[rowbase + r] = m_run[g][r];
        lb[rowbase + r] = lacc[g][r];
      }
    }
  }
}

// ---------------------------------------------------------------------------
// Kernel 3: merge 2 split-K partials + head-sum -> u. grid 4096, block 128.
// ---------------------------------------------------------------------------
__global__ __launch_bounds__(128) void merge_kernel(
    const _Float16* __restrict__ op, const float* __restrict__ mb,
    const float* __restrict__ lb, const float* __restrict__ Wm,
    float* __restrict__ u)
{
  __shared__ float sc[2][NHEAD];
  const int n = blockIdx.x, d = threadIdx.x;
  if (d < NHEAD) {
    const int h = d;
    const float m1 = mb[(size_t)h * NROWS + n];
    const float m2 = mb[(size_t)(NHEAD + h) * NROWS + n];
    const float l1 = lb[(size_t)h * NROWS + n];
    const float l2 = lb[(size_t)(NHEAD + h) * NROWS + n];
    const float m  = fmaxf(m1, m2);
    const float a1 = __expf(m1 - m), a2 = __expf(m2 - m);
    const float invL = Wm[h] / (l1 * a1 + l2 * a2);
    sc[0][h] = a1 * invL;
    sc[1][h] = a2 * invL;
  }
  __syncthreads();
  float acc = 0.f;
#pragma unroll
  for (int h = 0; h < NHEAD; h++) {
    acc += sc[0][h] * (float)op[((size_t)h * NROWS + n) * DDIM + d];
    acc += sc[1][h] * (float)op[((size_t)(NHEAD + h) * NROWS + n) * DDIM + d];
  }
  u[(size_t)n * DDIM + d] = acc;
}

// ---------------------------------------------------------------------------
// Kernel 4: y = x + relu((x+u) @ Wg^T + bg), 3-term bf16 MFMA, Wg in LDS.
// grid 64 (64-row tiles), block 256.
// ---------------------------------------------------------------------------
__global__ __launch_bounds__(256, 2) void mlp_kernel(
    const float* __restrict__ x, const float* __restrict__ u,
    const float* __restrict__ Wg, const float* __restrict__ bg,
    float* __restrict__ out)
{
  __shared__ alignas(16) unsigned short wghi[DDIM][72];
  __shared__ alignas(16) unsigned short wglo[DDIM][72];
  const int tid = threadIdx.x, lane = tid & 63, wave = tid >> 6;
  const int l4 = lane & 15, quad = lane >> 4;
  const int r0 = blockIdx.x * 64;

  floatx4 acc[8];
#pragma unroll
  for (int c = 0; c < 8; c++) acc[c] = (floatx4)0.f;

  for (int fh = 0; fh < 2; fh++) {
    for (int i = tid; i < DDIM * 64; i += 256) {
      const int ii = i >> 6, jl = i & 63;
      unsigned short hi, lo;
      split2(Wg[ii * DDIM + fh * 64 + jl], hi, lo);
      wghi[ii][jl] = hi; wglo[ii][jl] = lo;
    }
    __syncthreads();

    const size_t xoff = (size_t)(r0 + wave * 16 + l4) * DDIM + fh * 64 + quad * 8;
    short8 ah[2], al[2];
#pragma unroll
    for (int t2 = 0; t2 < 2; t2++) {
      float4 x0 = *(const float4*)(x + xoff + t2 * 32);
      float4 x1 = *(const float4*)(x + xoff + t2 * 32 + 4);
      float4 u0 = *(const float4*)(u + xoff + t2 * 32);
      float4 u1 = *(const float4*)(u + xoff + t2 * 32 + 4);
      float hv[8] = {x0.x + u0.x, x0.y + u0.y, x0.z + u0.z, x0.w + u0.w,
                     x1.x + u1.x, x1.y + u1.y, x1.z + u1.z, x1.w + u1.w};
#pragma unroll
      for (int j = 0; j < 8; j++) {
        unsigned short hi, lo; split2(hv[j], hi, lo);
        ah[t2][j] = (short)hi; al[t2][j] = (short)lo;
      }
    }
#pragma unroll
    for (int t2 = 0; t2 < 2; t2++) {
#pragma unroll
      for (int c = 0; c < 8; c++) {
        short8 bh = *(const short8*)(&wghi[c * 16 + l4][t2 * 32 + quad * 8]);
        short8 bl = *(const short8*)(&wglo[c * 16 + l4][t2 * 32 + quad * 8]);
        acc[c] = __builtin_amdgcn_mfma_f32_16x16x32_bf16(ah[t2], bh, acc[c], 0, 0, 0);
        acc[c] = __builtin_amdgcn_mfma_f32_16x16x32_bf16(al[t2], bh, acc[c], 0, 0, 0);
        acc[c] = __builtin_amdgcn_mfma_f32_16x16x32_bf16(ah[t2], bl, acc[c], 0, 0, 0);
      }
    }
    __syncthreads();
  }

  const int rbase = wave * 16 + quad * 4;
#pragma unroll
  for (int c = 0; c < 8; c++) {
    const int col = c * 16 + l4;
    const float bgf = bg[col];
#pragma unroll
    for (int r = 0; r < 4; r++) {
      const size_t idx = (size_t)(r0 + rbase + r) * DDIM + col;
      out[idx] = x[idx] + fmaxf(acc[c][r] + bgf, 0.f);
    }
  }
}

extern "C" void kernel_launch(void* const* d_in, const int* in_sizes, int n_in,
                              void* d_out, int out_size, void* d_ws, size_t ws_size,
                              hipStream_t stream) {
  float* out = (float*)d_out;
  const int fill_blocks = (out_size + 255) / 256;

  const bool ok_sizes =
      n_in == 7 &&
      in_sizes[0] == NROWS * DDIM &&
      in_sizes[1] == NHEAD * DDIM * DDIM &&
      in_sizes[2] == NHEAD * DDIM * DDIM &&
      in_sizes[3] == NHEAD * DDIM * DDIM &&
      in_sizes[4] == NHEAD &&
      in_sizes[5] == DDIM * DDIM &&
      in_sizes[6] == DDIM &&
      out_size == NROWS * DDIM;
  if (!ok_sizes) {
    fill_kernel<<<fill_blocks, 256, 0, stream>>>(out, 1000.f, out_size);
    return;
  }

  // ws: u 2MB + kfo 8.4 + vfo 8.4 + op(2) 16.8 + mb/lb 0.5 = 36.6MB
  const size_t HND = (size_t)NHEAD * NROWS * DDIM;
  const size_t ND  = (size_t)NROWS * DDIM;
  const size_t need = ND * 4 + 2 * HND * 2 + 2 * HND * 2 + 2 * NHEAD * NROWS * 8;
  if (ws_size < need) {
    fill_kernel<<<fill_blocks, 256, 0, stream>>>(out, 500.f, out_size);
    return;
  }

  const float* x  = (const float*)d_in[0];
  const float* Wk = (const float*)d_in[1];
  const float* Wq = (const float*)d_in[2];
  const float* Wv = (const float*)d_in[3];
  const float* Wm = (const float*)d_in[4];
  const float* Wg = (const float*)d_in[5];
  const float* bg = (const float*)d_in[6];

  float*     u   = (float*)d_ws;
  _Float16*  kfo = (_Float16*)(u + ND);
  _Float16*  vfo = kfo + HND;
  _Float16*  op  = vfo + HND;
  float*     mb  = (float*)(op + 2 * HND);
  float*     lb  = mb + 2 * NHEAD * NROWS;

  (void)hipGetLastError();
  proj_kernel<<<dim3(16, NHEAD, 2), 256, 0, stream>>>(x, Wk, Wv, kfo, vfo);
  flash_kernel<<<dim3(512), 256, 0, stream>>>(x, Wq, kfo, vfo, op, mb, lb);
  merge_kernel<<<dim3(4096), 128, 0, stream>>>(op, mb, lb, Wm, u);
  mlp_kernel<<<dim3(64), 256, 0, stream>>>(x, u, Wg, bg, out);
  if (hipGetLastError() != hipSuccess) {
    fill_kernel<<<fill_blocks, 256, 0, stream>>>(out, 2000.f, out_size);
  }
}